// Round 12
// baseline (205.628 us; speedup 1.0000x reference)
//
#include <hip/hip_runtime.h>
#include <hip/hip_fp16.h>

#define N_NODES 50000
#define E_EDGES 800000
#define SCAN_TILE 1024
#define SCAN_NBLK ((N_NODES + SCAN_TILE - 1) / SCAN_TILE)   // 49

__device__ __forceinline__ float sgpr_f(float x) {
    return __uint_as_float(__builtin_amdgcn_readfirstlane(__float_as_uint(x)));
}

#if defined(__has_builtin)
#if __has_builtin(__builtin_amdgcn_fdot2)
#define HAS_FDOT2 1
#endif
#endif

typedef _Float16 v2h_t __attribute__((ext_vector_type(2)));

__device__ __forceinline__ float fdot2f(__half2 a, __half2 b, float c) {
#ifdef HAS_FDOT2
    return __builtin_amdgcn_fdot2(*reinterpret_cast<v2h_t*>(&a),
                                  *reinterpret_cast<v2h_t*>(&b), c, false);
#else
    const float2 fa = __half22float2(a);
    const float2 fb = __half22float2(b);
    return fmaf(fa.x, fb.x, fmaf(fa.y, fb.y, c));
#endif
}

// packed relu: v_pk_max_f16 with inline constant 0
__device__ __forceinline__ __half2 relu_h2(__half2 x) {
    union { __half2 h; unsigned u; } a, r;
    a.h = x;
    asm("v_pk_max_f16 %0, %1, 0" : "=v"(r.u) : "v"(a.u));
    return r.h;
}

// DPP cross-lane moves (VALU pipe). 0xB1 = lane^1, 0x4E = lane^2,
// 0x141 = ROW_HALF_MIRROR (lane i <-> 7-i within aligned 8-lane groups).
template <int CTRL>
__device__ __forceinline__ float dpp_mov_f32(float x) {
    return __int_as_float(__builtin_amdgcn_update_dpp(
        0, __float_as_int(x), CTRL, 0xF, 0xF, true));
}
// full 8-lane (octet) all-reduce sum (validated r11)
__device__ __forceinline__ float oct_sum(float x) {
    x += dpp_mov_f32<0xB1>(x);
    x += dpp_mov_f32<0x4E>(x);
    x += dpp_mov_f32<0x141>(x);
    return x;
}

// ---------------------------------------------------------------------------
// Projection kernel: xq (N x 64 fp16) and xkv interleaved (N x 128 fp16:
// [0..63]=k-row, [64..127]=v-row) so the fused kernel's two gathers per edge
// land in one 256B neighborhood.
// ---------------------------------------------------------------------------
__global__ __launch_bounds__(256) void proj_kernel(
    const float* __restrict__ qin, const float* __restrict__ kin, const float* __restrict__ vin,
    const float* __restrict__ Wq, const float* __restrict__ bq,
    const float* __restrict__ Wk, const float* __restrict__ bk,
    const float* __restrict__ Wv, const float* __restrict__ bv,
    __half* __restrict__ xq, __half* __restrict__ xkv)
{
    __shared__ float Ws[3 * 4096];
    const int tid = threadIdx.x;
    #pragma unroll
    for (int it = 0; it < 16; ++it) {
        const int idx = it * 256 + tid;
        Ws[idx]        = Wq[idx];
        Ws[4096 + idx] = Wk[idx];
        Ws[8192 + idx] = Wv[idx];
    }
    __syncthreads();

    const int cg = tid & 15;
    const int rg = tid >> 4;
    const int c0 = cg * 4;
    const int base = blockIdx.x * 64 + rg * 4;

    const float* ins[3] = {qin, kin, vin};
    const float* bs[3]  = {bq, bk, bv};

    int rowi[4];
    #pragma unroll
    for (int rr = 0; rr < 4; ++rr)
        rowi[rr] = (base + rr < N_NODES) ? (base + rr) : (N_NODES - 1);

    #pragma unroll
    for (int m = 0; m < 3; ++m) {
        const float* in = ins[m];
        const float* Wm = &Ws[m * 4096];
        float4 acc[4];
        const float4 b4 = *reinterpret_cast<const float4*>(&bs[m][c0]);
        #pragma unroll
        for (int rr = 0; rr < 4; ++rr) acc[rr] = b4;

        for (int kk = 0; kk < 64; kk += 4) {
            float4 rv[4];
            #pragma unroll
            for (int rr = 0; rr < 4; ++rr)
                rv[rr] = *reinterpret_cast<const float4*>(&in[rowi[rr] * 64 + kk]);
            #pragma unroll
            for (int dk = 0; dk < 4; ++dk) {
                const float4 w4 = *reinterpret_cast<const float4*>(&Wm[(kk + dk) * 64 + c0]);
                #pragma unroll
                for (int rr = 0; rr < 4; ++rr) {
                    const float xs = reinterpret_cast<const float*>(&rv[rr])[dk];
                    acc[rr].x = fmaf(xs, w4.x, acc[rr].x);
                    acc[rr].y = fmaf(xs, w4.y, acc[rr].y);
                    acc[rr].z = fmaf(xs, w4.z, acc[rr].z);
                    acc[rr].w = fmaf(xs, w4.w, acc[rr].w);
                }
            }
        }
        #pragma unroll
        for (int rr = 0; rr < 4; ++rr) {
            if (base + rr < N_NODES) {
                union { __half2 h[2]; uint2 u; } pk;
                pk.h[0] = __floats2half2_rn(acc[rr].x, acc[rr].y);
                pk.h[1] = __floats2half2_rn(acc[rr].z, acc[rr].w);
                __half* obase;
                if (m == 0)      obase = &xq[(size_t)(base + rr) * 64 + c0];
                else if (m == 1) obase = &xkv[(size_t)(base + rr) * 128 + c0];
                else             obase = &xkv[(size_t)(base + rr) * 128 + 64 + c0];
                *reinterpret_cast<uint2*>(obase) = pk.u;
            }
        }
    }
}

// ---------------------------------------------------------------------------
// CSR build step 1: per-src degree histogram
// ---------------------------------------------------------------------------
__global__ __launch_bounds__(256) void hist_kernel(
    const int* __restrict__ eidx, int* __restrict__ cnt)
{
    const int e = blockIdx.x * 256 + threadIdx.x;
    atomicAdd(&cnt[eidx[2 * e]], 1);
}

// ---------------------------------------------------------------------------
// Hierarchical scan, step A: per-1024-element block sums (49 blocks).
// ---------------------------------------------------------------------------
__global__ __launch_bounds__(256) void scan_sums(
    const int* __restrict__ cnt, int* __restrict__ bsum)
{
    const int tid  = threadIdx.x;
    const int base = blockIdx.x * SCAN_TILE + tid * 4;
    int s = 0;
    if (base + 3 < N_NODES) {
        const int4 t = *reinterpret_cast<const int4*>(&cnt[base]);
        s = t.x + t.y + t.z + t.w;
    } else {
        #pragma unroll
        for (int i = 0; i < 4; ++i)
            if (base + i < N_NODES) s += cnt[base + i];
    }
    #pragma unroll
    for (int d = 1; d < 64; d <<= 1) s += __shfl_xor(s, d);
    __shared__ int ws[4];
    if ((tid & 63) == 0) ws[tid >> 6] = s;
    __syncthreads();
    if (tid == 0) bsum[blockIdx.x] = ws[0] + ws[1] + ws[2] + ws[3];
}

// ---------------------------------------------------------------------------
// Hierarchical scan, step B: exclusive scan of the 49 block sums (one wave).
// ---------------------------------------------------------------------------
__global__ __launch_bounds__(64) void scan_bsum(int* __restrict__ bsum)
{
    const int lane = threadIdx.x;
    const int v = (lane < SCAN_NBLK) ? bsum[lane] : 0;
    int incl = v;
    #pragma unroll
    for (int d = 1; d < 64; d <<= 1) {
        const int t = __shfl_up(incl, d);
        if (lane >= d) incl += t;
    }
    if (lane < SCAN_NBLK) bsum[lane] = incl - v;
}

// ---------------------------------------------------------------------------
// Hierarchical scan, step C: local exclusive scan + block offset.
// Writes off[] and re-purposes cnt[] (in-place) as the scatter cursor.
// ---------------------------------------------------------------------------
__global__ __launch_bounds__(256) void scan_final(
    int* __restrict__ cnt, const int* __restrict__ bsum, int* __restrict__ off)
{
    const int tid  = threadIdx.x;
    const int base = blockIdx.x * SCAN_TILE + tid * 4;

    int v0 = 0, v1 = 0, v2 = 0, v3 = 0;
    if (base + 3 < N_NODES) {
        const int4 t = *reinterpret_cast<const int4*>(&cnt[base]);
        v0 = t.x; v1 = t.y; v2 = t.z; v3 = t.w;
    } else {
        if (base + 0 < N_NODES) v0 = cnt[base + 0];
        if (base + 1 < N_NODES) v1 = cnt[base + 1];
        if (base + 2 < N_NODES) v2 = cnt[base + 2];
        if (base + 3 < N_NODES) v3 = cnt[base + 3];
    }
    const int s = v0 + v1 + v2 + v3;

    int incl = s;
    #pragma unroll
    for (int d = 1; d < 64; d <<= 1) {
        const int t = __shfl_up(incl, d);
        if ((tid & 63) >= d) incl += t;
    }
    __shared__ int wsum[4];
    const int wave = tid >> 6;
    if ((tid & 63) == 63) wsum[wave] = incl;
    __syncthreads();
    int woff = 0;
    #pragma unroll
    for (int w = 0; w < 3; ++w)
        if (w < wave) woff += wsum[w];

    int run = bsum[blockIdx.x] + woff + (incl - s);
    if (base + 0 < N_NODES) { off[base + 0] = run; cnt[base + 0] = run; run += v0; }
    if (base + 1 < N_NODES) { off[base + 1] = run; cnt[base + 1] = run; run += v1; }
    if (base + 2 < N_NODES) { off[base + 2] = run; cnt[base + 2] = run; run += v2; }
    if (base + 3 < N_NODES) { off[base + 3] = run; cnt[base + 3] = run; run += v3; }

    if (blockIdx.x == 0 && tid == 0) off[N_NODES] = E_EDGES;
}

// ---------------------------------------------------------------------------
// Scatter + p_r precompute (r2-proven): stream edges rows (coalesced),
// compute p = edges[e].Wp + bp, scatter only the 8B {p,dst} record.
// ---------------------------------------------------------------------------
__global__ __launch_bounds__(256) void scatter_p(
    const int* __restrict__ eidx, const float* __restrict__ edges,
    const float* __restrict__ Wp, const float* __restrict__ bp,
    int* __restrict__ cursor, float2* __restrict__ ep2)
{
    const int e = blockIdx.x * 256 + threadIdx.x;
    const int src = eidx[2 * e];
    const int dst = eidx[2 * e + 1];

    float pr = bp[0];
    #pragma unroll
    for (int q4 = 0; q4 < 4; ++q4) {
        const float4 ev = *reinterpret_cast<const float4*>(&edges[(size_t)e * 16 + q4 * 4]);
        const float4 wv = *reinterpret_cast<const float4*>(&Wp[q4 * 4]);
        pr = fmaf(ev.x, wv.x, pr);
        pr = fmaf(ev.y, wv.y, pr);
        pr = fmaf(ev.z, wv.z, pr);
        pr = fmaf(ev.w, wv.w, pr);
    }

    const int pos = atomicAdd(&cursor[src], 1);
    ep2[pos] = make_float2(pr, __int_as_float(dst));
}

// ---------------------------------------------------------------------------
// Fused node kernel: 16 lanes per node (2 sub-octets, alternate edges).
// Lane r owns channels 8r..8r+7. Per edge: linear {p,dst} record, one 256B
// xkv neighborhood gather, DPP-butterfly h1 all-reduce, lane-local logits +
// softmax (W2/b1/b2 in SGPRs), accumulate. 2-stage software pipeline:
// records prefetched 2 ahead, gathers issued 1 iteration ahead.
// ---------------------------------------------------------------------------
__global__ __launch_bounds__(256) void node_fused(
    const int* __restrict__ off, const float2* __restrict__ ep2,
    const float* __restrict__ W1, const float* __restrict__ b1,
    const float* __restrict__ W2, const float* __restrict__ b2,
    const __half* __restrict__ xq, const __half* __restrict__ xkv,
    float* __restrict__ out)
{
    const int tid  = threadIdx.x;
    const int lane = tid & 63;
    const int grp  = lane >> 4;        // 4 nodes per wave
    const int sub  = (lane >> 3) & 1;  // sub-octet: alternate edges
    const int r    = lane & 7;         // channel block 8r..8r+7
    const int wave = tid >> 6;

    // W1 rows 8r..8r+7, half2-packed over row pairs (32 VGPRs)
    __half2 W1h[4][8];
    #pragma unroll
    for (int i = 0; i < 4; ++i) {
        const float4 a0 = *reinterpret_cast<const float4*>(&W1[(8 * r + 2 * i) * 8]);
        const float4 a1 = *reinterpret_cast<const float4*>(&W1[(8 * r + 2 * i) * 8 + 4]);
        const float4 c0 = *reinterpret_cast<const float4*>(&W1[(8 * r + 2 * i + 1) * 8]);
        const float4 c1 = *reinterpret_cast<const float4*>(&W1[(8 * r + 2 * i + 1) * 8 + 4]);
        W1h[i][0] = __floats2half2_rn(a0.x, c0.x);
        W1h[i][1] = __floats2half2_rn(a0.y, c0.y);
        W1h[i][2] = __floats2half2_rn(a0.z, c0.z);
        W1h[i][3] = __floats2half2_rn(a0.w, c0.w);
        W1h[i][4] = __floats2half2_rn(a1.x, c1.x);
        W1h[i][5] = __floats2half2_rn(a1.y, c1.y);
        W1h[i][6] = __floats2half2_rn(a1.z, c1.z);
        W1h[i][7] = __floats2half2_rn(a1.w, c1.w);
    }
    // uniform weights -> SGPRs (r5-validated pattern)
    float W2u[8][8];
    #pragma unroll
    for (int jj = 0; jj < 8; ++jj)
        #pragma unroll
        for (int j2 = 0; j2 < 8; ++j2)
            W2u[jj][j2] = sgpr_f(W2[jj * 8 + j2]);
    float b1u[8], b2u[8];
    #pragma unroll
    for (int j2 = 0; j2 < 8; ++j2) { b1u[j2] = sgpr_f(b1[j2]); b2u[j2] = sgpr_f(b2[j2]); }

    const int node = blockIdx.x * 16 + wave * 4 + grp;   // grid exact: < 50000

    const int beg = off[node];
    const int end = off[node + 1];

    // xq slice: one 16B load (channels 8r..8r+7)
    uint4 q4u = *reinterpret_cast<const uint4*>(&xq[(size_t)node * 64 + 8 * r]);
    const __half2* qh = reinterpret_cast<const __half2*>(&q4u);

    float acc[8];
    #pragma unroll
    for (int i = 0; i < 8; ++i) acc[i] = 0.f;

    int j = beg + sub;
    if (j < end) {
        // ---- pipeline prologue ----
        float2 e0 = ep2[j];
        const int jc1 = (j + 2 < end) ? (j + 2) : (end - 1);
        float2 e1 = ep2[jc1];
        size_t gb = (size_t)__float_as_int(e0.y) * 128 + 8 * r;
        uint4 k4 = *reinterpret_cast<const uint4*>(&xkv[gb]);
        uint4 v4 = *reinterpret_cast<const uint4*>(&xkv[gb + 64]);

        for (; j < end; j += 2) {
            // issue next gathers (e1) + next-next record — hidden under compute
            const size_t gbn = (size_t)__float_as_int(e1.y) * 128 + 8 * r;
            uint4 k4n = *reinterpret_cast<const uint4*>(&xkv[gbn]);
            uint4 v4n = *reinterpret_cast<const uint4*>(&xkv[gbn + 64]);
            const int jc2 = (j + 4 < end) ? (j + 4) : (end - 1);
            float2 e2r = ep2[jc2];

            const float p = e0.x;
            const __half2 p2 = __float2half2_rn(p);
            const __half2* kh = reinterpret_cast<const __half2*>(&k4);

            // h1 partials over this lane's 8 channels
            float part[8];
            #pragma unroll
            for (int jj = 0; jj < 8; ++jj) part[jj] = 0.f;
            #pragma unroll
            for (int i = 0; i < 4; ++i) {
                const __half2 d = relu_h2(__hadd2(__hsub2(kh[i], qh[i]), p2));
                #pragma unroll
                for (int jj = 0; jj < 8; ++jj)
                    part[jj] = fdot2f(d, W1h[i][jj], part[jj]);
            }
            // octet all-reduce (DPP): every lane holds full h1
            #pragma unroll
            for (int jj = 0; jj < 8; ++jj) part[jj] = oct_sum(part[jj]);

            // lane-local logits + softmax (no cross-lane ops)
            float g[8];
            #pragma unroll
            for (int jj = 0; jj < 8; ++jj) g[jj] = fmaxf(part[jj] + b1u[jj], 0.f);
            float h2[8];
            #pragma unroll
            for (int j2 = 0; j2 < 8; ++j2) h2[j2] = b2u[j2];
            #pragma unroll
            for (int jj = 0; jj < 8; ++jj)
                #pragma unroll
                for (int j2 = 0; j2 < 8; ++j2)
                    h2[j2] = fmaf(g[jj], W2u[jj][j2], h2[j2]);

            float mx = h2[0];
            #pragma unroll
            for (int j2 = 1; j2 < 8; ++j2) mx = fmaxf(mx, h2[j2]);
            float ex[8], s = 0.f;
            #pragma unroll
            for (int j2 = 0; j2 < 8; ++j2) { ex[j2] = __expf(h2[j2] - mx); s += ex[j2]; }
            const float inv = 1.f / s;

            // accumulate: channel 8r+i gets weight ex[i]*inv
            const __half2* vh = reinterpret_cast<const __half2*>(&v4);
            #pragma unroll
            for (int i = 0; i < 4; ++i) {
                const float2 fv = __half22float2(vh[i]);
                acc[2 * i]     = fmaf(fv.x + p, ex[2 * i] * inv,     acc[2 * i]);
                acc[2 * i + 1] = fmaf(fv.y + p, ex[2 * i + 1] * inv, acc[2 * i + 1]);
            }

            // rotate pipeline
            e0 = e1; e1 = e2r; k4 = k4n; v4 = v4n;
        }
    }

    // merge the two sub-octets
    #pragma unroll
    for (int i = 0; i < 8; ++i)
        acc[i] += __shfl_xor(acc[i], 8);

    if (sub == 0) {
        float* orow = &out[(size_t)node * 64 + 8 * r];
        *reinterpret_cast<float4*>(orow)     = make_float4(acc[0], acc[1], acc[2], acc[3]);
        *reinterpret_cast<float4*>(orow + 4) = make_float4(acc[4], acc[5], acc[6], acc[7]);
    }
}

extern "C" void kernel_launch(void* const* d_in, const int* in_sizes, int n_in,
                              void* d_out, int out_size, void* d_ws, size_t ws_size,
                              hipStream_t stream) {
    const float* q     = (const float*)d_in[0];
    const float* k     = (const float*)d_in[1];
    const float* v     = (const float*)d_in[2];
    const float* edges = (const float*)d_in[3];
    const int*   eidx  = (const int*)d_in[4];
    const float* Wq    = (const float*)d_in[5];
    const float* bq    = (const float*)d_in[6];
    const float* Wk    = (const float*)d_in[7];
    const float* bk    = (const float*)d_in[8];
    const float* Wv    = (const float*)d_in[9];
    const float* bv    = (const float*)d_in[10];
    const float* Wp    = (const float*)d_in[11];
    const float* bp    = (const float*)d_in[12];
    const float* W1    = (const float*)d_in[13];
    const float* b1    = (const float*)d_in[14];
    const float* W2    = (const float*)d_in[15];
    const float* b2    = (const float*)d_in[16];
    float* out = (float*)d_out;

    // workspace layout
    char* ws = (char*)d_ws;
    __half* xq  = (__half*)ws;         ws += (size_t)N_NODES * 64 * sizeof(__half);    // 6.4 MB
    __half* xkv = (__half*)ws;         ws += (size_t)N_NODES * 128 * sizeof(__half);   // 12.8 MB
    int* cnt  = (int*)ws;              ws += (size_t)(N_NODES + 64) * sizeof(int);
    int* off  = (int*)ws;              ws += (size_t)(N_NODES + 64) * sizeof(int);
    int* bsum = (int*)ws;              ws += (size_t)64 * sizeof(int);
    float2* ep2 = (float2*)ws;         ws += (size_t)E_EDGES * sizeof(float2);         // 6.4 MB

    hipMemsetAsync(cnt, 0, (size_t)N_NODES * sizeof(int), stream);

    hist_kernel<<<dim3(E_EDGES / 256), dim3(256), 0, stream>>>(eidx, cnt);

    scan_sums<<<dim3(SCAN_NBLK), dim3(256), 0, stream>>>(cnt, bsum);
    scan_bsum<<<dim3(1), dim3(64), 0, stream>>>(bsum);
    scan_final<<<dim3(SCAN_NBLK), dim3(256), 0, stream>>>(cnt, bsum, off);

    scatter_p<<<dim3(E_EDGES / 256), dim3(256), 0, stream>>>(
        eidx, edges, Wp, bp, cnt, ep2);

    proj_kernel<<<dim3((N_NODES + 63) / 64), dim3(256), 0, stream>>>(
        q, k, v, Wq, bq, Wk, bk, Wv, bv, xq, xkv);

    node_fused<<<dim3(N_NODES / 16), dim3(256), 0, stream>>>(
        off, ep2, W1, b1, W2, b2, xq, xkv, out);
}